// Round 1
// baseline (498.559 us; speedup 1.0000x reference)
//
#include <hip/hip_runtime.h>
#include <hip/hip_bf16.h>
#include <cstdint>
#include <cstddef>

#define D_DIM 2048
#define L_SEQ 2048
#define B_SZ 4
#define M_ROWS (B_SZ * L_SEQ)   /* 8192 */
#define NT_COLS (3 * D_DIM)     /* 6144: seg0=A, seg1=dt, seg2=rawB */
#define NCH 16
#define CHUNK (L_SEQ / NCH)     /* 128 */

typedef __bf16 bf16_t;
typedef bf16_t bf16x4 __attribute__((ext_vector_type(4)));
typedef bf16_t bf16x8 __attribute__((ext_vector_type(8)));
typedef float f32x4 __attribute__((ext_vector_type(4)));

__device__ __forceinline__ void gl_lds16(const void* g, void* l) {
    __builtin_amdgcn_global_load_lds(
        (const __attribute__((address_space(1))) unsigned int*)g,
        (__attribute__((address_space(3))) unsigned int*)l, 16, 0, 0);
}

// ---------------- convert force f32 -> bf16 (vectorized) ----------------
__global__ __launch_bounds__(256) void cvt_bf16_kernel(
    const float* __restrict__ in, bf16_t* __restrict__ out, int n4)
{
    int i = blockIdx.x * 256 + threadIdx.x;
    if (i >= n4) return;
    float4 f = ((const float4*)in)[i];
    bf16x4 o;
    o[0] = (bf16_t)f.x; o[1] = (bf16_t)f.y; o[2] = (bf16_t)f.z; o[3] = (bf16_t)f.w;
    ((bf16x4*)out)[i] = o;
}

// ---------------- transpose W[k][j] -> Wt[j][k] with f32->bf16 ----------------
__global__ __launch_bounds__(256) void transpose_w_kernel(
    const float* __restrict__ W, bf16_t* __restrict__ Wt)
{
    __shared__ float tile[32][33];
    int j0 = blockIdx.x * 32, k0 = blockIdx.y * 32;
    int tx = threadIdx.x, ty = threadIdx.y;      // block (32, 8)
#pragma unroll
    for (int i = 0; i < 4; i++) {
        int k = k0 + ty + i * 8;
        tile[ty + i * 8][tx] = W[(size_t)k * D_DIM + j0 + tx];
    }
    __syncthreads();
#pragma unroll
    for (int i = 0; i < 4; i++) {
        int j = j0 + ty + i * 8;
        Wt[(size_t)j * D_DIM + k0 + tx] = (bf16_t)tile[tx][ty + i * 8];
    }
}

// ---------------- fused bf16 GEMM: [8192 x 2048] @ [2048 x 6144] ----------------
// m97 structure: 128x128 tile, BK=32, 4 waves (2x2), global_load_lds width 16.
__global__ __launch_bounds__(256) void gemm_fused_kernel(
    const bf16_t* __restrict__ Abf,   // force bf16 [8192][2048]
    const bf16_t* __restrict__ Wt,    // [6144][2048] (W^T, concat A|dt|B)
    const float* __restrict__ bA, const float* __restrict__ bdt,
    const float* __restrict__ bB, const float* __restrict__ scales,
    float* __restrict__ outA,         // -> d_out x-region (staging)
    float* __restrict__ outDT,        // -> ws
    float* __restrict__ outB)         // -> d_out v-region (staging)
{
    __shared__ bf16_t lds_a[128 * 32];
    __shared__ bf16_t lds_b[128 * 32];

    const int bm0 = blockIdx.x * 128;         // M block
    const int bn0 = blockIdx.y * 128;         // NT block
    const int t = threadIdx.x;
    const int lane = t & 63, w = t >> 6;
    const int wr = (w >> 1) * 64;             // wave row offset in tile
    const int wc = (w & 1) * 64;              // wave col offset in tile

    f32x4 acc[4][4] = {};

    const int lin0 = t, lin1 = t + 256;
    const int ar0 = lin0 >> 2, ac0 = (lin0 & 3) * 8;
    const int ar1 = lin1 >> 2, ac1 = (lin1 & 3) * 8;
    const int frow = lane & 15;
    const int fk = (lane >> 4) * 8;

    for (int k0 = 0; k0 < D_DIM; k0 += 32) {
        gl_lds16(Abf + (size_t)(bm0 + ar0) * D_DIM + k0 + ac0, lds_a + w * 512);
        gl_lds16(Abf + (size_t)(bm0 + ar1) * D_DIM + k0 + ac1, lds_a + 2048 + w * 512);
        gl_lds16(Wt  + (size_t)(bn0 + ar0) * D_DIM + k0 + ac0, lds_b + w * 512);
        gl_lds16(Wt  + (size_t)(bn0 + ar1) * D_DIM + k0 + ac1, lds_b + 2048 + w * 512);
        __syncthreads();

        bf16x8 af[4], bfr[4];
#pragma unroll
        for (int m = 0; m < 4; m++)
            af[m] = *(const bf16x8*)&lds_a[(wr + m * 16 + frow) * 32 + fk];
#pragma unroll
        for (int n = 0; n < 4; n++)
            bfr[n] = *(const bf16x8*)&lds_b[(wc + n * 16 + frow) * 32 + fk];
#pragma unroll
        for (int m = 0; m < 4; m++)
#pragma unroll
            for (int n = 0; n < 4; n++)
                acc[m][n] = __builtin_amdgcn_mfma_f32_16x16x32_bf16(
                    af[m], bfr[n], acc[m][n], 0, 0, 0);
        __syncthreads();
    }

    // epilogue: C/D layout col = lane&15, row = (lane>>4)*4 + reg  [m89-verified]
    const int seg = bn0 >> 11;                        // 0=A, 1=dt, 2=rawB
    const int dbase = (bn0 & 2047) + wc + (lane & 15);
    const int rowbase = bm0 + wr + ((lane >> 4) << 2);
#pragma unroll
    for (int m = 0; m < 4; m++) {
#pragma unroll
        for (int n = 0; n < 4; n++) {
            int d = dbase + n * 16;
#pragma unroll
            for (int r = 0; r < 4; r++) {
                int gm = rowbase + m * 16 + r;
                size_t idx = (size_t)gm * D_DIM + d;
                float val = acc[m][n][r];
                if (seg == 0) {
                    outA[idx] = 1.0f / (1.0f + __expf(-(val + bA[d])));
                } else if (seg == 1) {
                    float xx = val + bdt[d];
                    float sp = xx > 0.f ? xx + log1pf(__expf(-xx)) : log1pf(__expf(xx));
                    outDT[idx] = sp * 0.1f * scales[d];
                } else {
                    outB[idx] = val + bB[d];
                }
            }
        }
    }
}

// ---------------- scan pass 1: per-chunk affine aggregates ----------------
// step map: v' = a v + bv ; x' = x + dt v'  =>  (P,R,u,w):
//   v' = P v + u ; x' = R v + x + w
__global__ __launch_bounds__(256) void scan_pass1_kernel(
    const float* __restrict__ Aarr, const float* __restrict__ Braw,
    const float* __restrict__ dtarr, float4* __restrict__ agg)
{
    int tid = blockIdx.x * 256 + threadIdx.x;   // 131072
    int d = tid & (D_DIM - 1);
    int c = (tid >> 11) & (NCH - 1);
    int b = tid >> 15;
    size_t base = ((size_t)b * L_SEQ + c * CHUNK) * D_DIM + d;
    float P = 1.f, R = 0.f, U = 0.f, Wg = 0.f;
#pragma unroll 4
    for (int tt = 0; tt < CHUNK; tt++) {
        size_t idx = base + (size_t)tt * D_DIM;
        float a = Aarr[idx], rb = Braw[idx], dt = dtarr[idx];
        float bv = rb * dt;
        float da = dt * a;
        R = da * P + R;            // uses old P
        Wg = da * U + dt * bv + Wg; // uses old U
        U = a * U + bv;
        P = a * P;
    }
    agg[tid] = make_float4(P, R, U, Wg);
}

// ---------------- scan pass 2: combine chunk aggregates ----------------
__global__ __launch_bounds__(256) void scan_pass2_kernel(
    const float4* __restrict__ agg, float2* __restrict__ pre)
{
    int tid = blockIdx.x * 256 + threadIdx.x;   // 8192
    int d = tid & (D_DIM - 1);
    int b = tid >> 11;
    float v = 0.f, x = 0.f;
#pragma unroll
    for (int c = 0; c < NCH; c++) {
        int i = ((b * NCH + c) << 11) + d;
        float4 g = agg[i];
        pre[i] = make_float2(v, x);             // state entering chunk c
        float vn = g.x * v + g.z;               // P v + u
        x = g.y * v + x + g.w;                  // R v + x + w   (old v)
        v = vn;
    }
}

// ---------------- scan pass 3: replay chunk, write outputs in place ----------------
__global__ __launch_bounds__(256) void scan_pass3_kernel(
    const float* __restrict__ dtarr, const float2* __restrict__ pre,
    float* __restrict__ xout /* holds A, becomes x_seq */,
    float* __restrict__ vout /* holds rawB, becomes v_seq */)
{
    int tid = blockIdx.x * 256 + threadIdx.x;
    int d = tid & (D_DIM - 1);
    int c = (tid >> 11) & (NCH - 1);
    int b = tid >> 15;
    float2 s = pre[((b * NCH + c) << 11) + d];
    float v = s.x, x = s.y;
    size_t base = ((size_t)b * L_SEQ + c * CHUNK) * D_DIM + d;
#pragma unroll 4
    for (int tt = 0; tt < CHUNK; tt++) {
        size_t idx = base + (size_t)tt * D_DIM;
        float a = xout[idx];       // A (staged)
        float rb = vout[idx];      // rawB (staged)
        float dt = dtarr[idx];
        v = a * v + rb * dt;
        x = x + v * dt;
        vout[idx] = v;             // same element: read-before-write, same thread
        xout[idx] = x;
    }
}

extern "C" void kernel_launch(void* const* d_in, const int* in_sizes, int n_in,
                              void* d_out, int out_size, void* d_ws, size_t ws_size,
                              hipStream_t stream) {
    // inputs: 0:x 1:v 2:force 3:WA 4:bA 5:WB 6:bB 7:Wdt 8:bdt 9:scales
    const float* force  = (const float*)d_in[2];
    const float* WA     = (const float*)d_in[3];
    const float* bA     = (const float*)d_in[4];
    const float* WB     = (const float*)d_in[5];
    const float* bB     = (const float*)d_in[6];
    const float* Wdt    = (const float*)d_in[7];
    const float* bdt    = (const float*)d_in[8];
    const float* scales = (const float*)d_in[9];

    float* xout = (float*)d_out;                          // x_seq [8192*2048]
    float* vout = xout + (size_t)M_ROWS * D_DIM;          // v_seq

    char* ws = (char*)d_ws;
    bf16_t* fbf = (bf16_t*)ws;                                     // 32 MB
    bf16_t* wt  = (bf16_t*)(ws + (size_t)33554432);                // 24 MB
    float*  dtv = (float*)(ws + (size_t)33554432 + 25165824);      // 64 MB
    float4* agg = (float4*)(ws + (size_t)33554432 + 25165824 + 67108864); // 2 MB
    float2* pre = (float2*)(ws + (size_t)33554432 + 25165824 + 67108864 + 2097152); // 1 MB

    // 1) force -> bf16
    {
        int n4 = M_ROWS * D_DIM / 4;
        cvt_bf16_kernel<<<n4 / 256, 256, 0, stream>>>(force, fbf, n4);
    }
    // 2) transpose + convert weights into concat [6144][2048]: A | dt | B
    {
        dim3 grid(D_DIM / 32, D_DIM / 32), block(32, 8);
        transpose_w_kernel<<<grid, block, 0, stream>>>(WA,  wt);
        transpose_w_kernel<<<grid, block, 0, stream>>>(Wdt, wt + (size_t)D_DIM * D_DIM);
        transpose_w_kernel<<<grid, block, 0, stream>>>(WB,  wt + (size_t)2 * D_DIM * D_DIM);
    }
    // 3) fused GEMM + activations
    {
        dim3 grid(M_ROWS / 128, NT_COLS / 128);
        gemm_fused_kernel<<<grid, 256, 0, stream>>>(fbf, wt, bA, bdt, bB, scales,
                                                    xout, dtv, vout);
    }
    // 4-6) chunked associative scan
    scan_pass1_kernel<<<(B_SZ * NCH * D_DIM) / 256, 256, 0, stream>>>(xout, vout, dtv, agg);
    scan_pass2_kernel<<<(B_SZ * D_DIM) / 256, 256, 0, stream>>>(agg, pre);
    scan_pass3_kernel<<<(B_SZ * NCH * D_DIM) / 256, 256, 0, stream>>>(dtv, pre, xout, vout);
}